// Round 8
// baseline (188.811 us; speedup 1.0000x reference)
//
#include <hip/hip_runtime.h>

#define B_ 4
#define N_ 2048
#define D_ 512
#define H_ 8
#define SC 16                // node rows per chunk
#define NCH 128              // 2048/16 — CLS row (s=0) folded analytically into K3
#define NBLK (NCH * B_)      // 512 = exactly 2 blocks/CU

// workspace layout (float offsets). w/z/cnt zeroed by K1 (poison-proof); rest write-before-read.
#define TQ_OFF   64                                 // [H][D] = 4096
#define W2_OFF   8192                               // [B][H][D] = 16384 (atomic-accumulated)
#define Z_OFF    (W2_OFF + B_ * H_ * D_)            // [B][H] = 32 (atomic-accumulated)
#define CNT_OFF  (Z_OFF + 32)                       // [B] u32 LN tickets (inside zeroed span)
#define O0_OFF   (CNT_OFF + 32)                     // [B][D]
#define Y_OFF    (O0_OFF + B_ * D_)                 // [B][D]

__device__ __forceinline__ float wave_reduce_sum(float v) {
    #pragma unroll
    for (int off = 32; off > 0; off >>= 1) v += __shfl_down(v, off, 64);
    return v;
}
__device__ __forceinline__ float wave_allreduce_sum(float v) {
    #pragma unroll
    for (int off = 1; off < 64; off <<= 1) v += __shfl_xor(v, off, 64);
    return v;
}
__device__ __forceinline__ float dot8(float4 a, float4 b, float4 c, float4 d) {
    return a.x*b.x + a.y*b.y + a.z*b.z + a.w*b.w
         + c.x*d.x + c.y*d.y + c.z*d.z + c.w*d.w;
}

// ---- K1: 64 blocks. 0..31: tq producers (proven body). 32..63: zero w/z/cnt.
//          (R7 lesson: the 484-block nf prefetch serialized a full HBM read BEFORE K2
//           while hiding it behind 2us of tq work — dropped; K2 eats the read at BW.)
__global__ void __launch_bounds__(512)
setup_kernel(const float* __restrict__ ct,
             const float* __restrict__ Wq, const float* __restrict__ bq,
             const float* __restrict__ Wk, float* __restrict__ ws) {
    __shared__ float q0s[64];
    __shared__ float part[4][128];
    const int blk = blockIdx.x;
    const int tid = threadIdx.x, wv = tid >> 6, lane = tid & 63;

    if (blk >= 32) {
        // zero accumulators: w2[16384] across 32 blocks; block 32 also z[32]+cnt[4]
        ws[W2_OFF + (size_t)(blk - 32) * 512 + tid] = 0.f;
        if (blk == 32 && tid < 36) ws[Z_OFF + tid] = 0.f;
        return;
    }

    // tq producer (proven): h = blk>>2, column-quarter jq = blk&3
    const int h = blk >> 2, jq = blk & 3;
    const float4* c4 = (const float4*)ct;
    float4 ca = c4[lane * 2], cb = c4[lane * 2 + 1];
    #pragma unroll
    for (int i = 0; i < 8; ++i) {
        int rl = wv + 8 * i;
        int r  = h * 64 + rl;
        const float4* row = (const float4*)(Wq + (size_t)r * D_);
        float4 a = row[lane * 2], b = row[lane * 2 + 1];
        float acc = dot8(a, ca, b, cb);
        acc = wave_reduce_sum(acc);
        if (lane == 0) q0s[rl] = acc + bq[r];
    }
    __syncthreads();
    {
        int jj = tid & 127, g = tid >> 7;
        int j  = jq * 128 + jj;
        float acc = 0.f;
        #pragma unroll
        for (int d = 0; d < 16; ++d) {
            int d2 = g * 16 + d;
            acc += q0s[d2] * Wk[(size_t)(h * 64 + d2) * D_ + j];
        }
        part[g][jj] = acc;
    }
    __syncthreads();
    if (tid < 128)
        ws[TQ_OFF + h * D_ + jq * 128 + tid] =
            part[0][tid] + part[1][tid] + part[2][tid] + part[3][tid];
}

// ---- K2: fused scores+wsum per (chunk,b) — node rows only (s>=1), branch-free,
//          grid exactly 512 = 2 blocks/CU. Proven math; atomic accumulate into w2/z.
__global__ void __launch_bounds__(512)
scores_wsum_kernel(const float* __restrict__ nf, const float* __restrict__ masks,
                   float* __restrict__ ws) {
    __shared__ float sa[H_ * SC];        // sa[(h<<4)+ss]
    const int blk = blockIdx.x;
    const int tid = threadIdx.x, wv = tid >> 6, lane = tid & 63;
    const int chunk = blk >> 2, b4 = blk & 3;
    const int n0 = chunk * SC;           // node index base (nf row), s = n0+ss+1

    // B1: attn weights for own 16 node rows -> LDS (proven math, no CLS branch)
    {
        const float4* t4 = (const float4*)(ws + TQ_OFF);
        #pragma unroll
        for (int i = 0; i < 2; ++i) {
            int ss = wv + 8 * i;             // 0..15
            int n  = n0 + ss;
            const float4* x4 = (const float4*)(nf + ((size_t)b4 * N_ + n) * D_);
            float4 xa = x4[lane], xb = x4[64 + lane];
            float gate = (masks[b4 * N_ + n] != 0.0f) ? 1.0f : 0.0f;
            float p[H_];
            #pragma unroll
            for (int h = 0; h < H_; ++h) {
                float4 ta = t4[h * 128 + lane], tb = t4[h * 128 + 64 + lane];
                p[h] = dot8(ta, xa, tb, xb);
                p[h] = wave_allreduce_sum(p[h]);
            }
            if (lane == 0) {
                #pragma unroll
                for (int h = 0; h < H_; ++h)
                    sa[(h << 4) + ss] = gate * __expf(p[h] * 0.125f);
            }
        }
    }
    __syncthreads();
    // B2: weighted sums (rows L1/L2-hot from B1) -> atomic accumulate
    {
        float acc[H_];
        #pragma unroll
        for (int h = 0; h < H_; ++h) acc[h] = 0.f;
        #pragma unroll 4
        for (int ss = 0; ss < SC; ++ss) {
            float xv = nf[((size_t)b4 * N_ + n0 + ss) * D_ + tid];
            #pragma unroll
            for (int h = 0; h < H_; ++h) acc[h] += sa[(h << 4) + ss] * xv;
        }
        #pragma unroll
        for (int h = 0; h < H_; ++h)
            atomicAdd(ws + W2_OFF + (size_t)(b4 * H_ + h) * D_ + tid, acc[h]);
        if (tid < H_) {
            float z = 0.f;
            #pragma unroll
            for (int ss = 0; ss < SC; ++ss) z += sa[(tid << 4) + ss];
            atomicAdd(ws + Z_OFF + b4 * H_ + tid, z);
        }
    }
}

// ---- K3: o0[b, g*8+wv] = Wv[r,:].(w2 + a0*ct)/(z + a0) + bv[r].  grid(256) x 512.
//          a0 = exp(tq[head].ct / 8) — CLS key folded analytically (computed per
//          block by wave 0 from L2-hot tq; CLS gate is always 1 in the reference).
__global__ void __launch_bounds__(512)
wv_kernel(const float* __restrict__ Wv, const float* __restrict__ bv,
          const float* __restrict__ ct, float* __restrict__ ws) {
    __shared__ float a0s;
    const int blk = blockIdx.x;
    const int b = blk >> 6, g = blk & 63;
    const int wv = threadIdx.x >> 6, lane = threadIdx.x & 63;
    const int head = g >> 3;             // rows g*8..g*8+7 share one head (8 | 64)
    const float4* c4 = (const float4*)ct;
    float4 ca = c4[lane * 2], cb = c4[lane * 2 + 1];
    if (wv == 0) {
        const float4* t4 = (const float4*)(ws + TQ_OFF + (size_t)head * D_);
        float4 ta = t4[lane * 2], tb = t4[lane * 2 + 1];
        float d = dot8(ta, ca, tb, cb);
        d = wave_allreduce_sum(d);
        if (lane == 0) a0s = __expf(d * 0.125f);
    }
    __syncthreads();
    const float a0 = a0s;
    const float zi = 1.0f / (ws[Z_OFF + b * H_ + head] + a0);
    const int r = g * 8 + wv;
    const float4* wr = (const float4*)(ws + W2_OFF + (size_t)(b * H_ + head) * D_);
    float4 wa = wr[lane * 2], wb = wr[lane * 2 + 1];
    wa.x += a0 * ca.x; wa.y += a0 * ca.y; wa.z += a0 * ca.z; wa.w += a0 * ca.w;
    wb.x += a0 * cb.x; wb.y += a0 * cb.y; wb.z += a0 * cb.z; wb.w += a0 * cb.w;
    const float4* row = (const float4*)(Wv + (size_t)r * D_);
    float4 a = row[lane * 2], c = row[lane * 2 + 1];
    float acc = dot8(a, wa, c, wb);
    acc = wave_reduce_sum(acc);
    if (lane == 0) ws[O0_OFF + b * D_ + r] = acc * zi + bv[r];
}

// ---- K4: y[b, g*8+wv] = Wo[r,:].o0[b,:] + bo[r] + ct[r] (proven body), then the
//          LAST block per batch (single acq_rel ticket RMW on cnt[b] — no polling) runs LN.
__global__ void __launch_bounds__(512)
wo_ln_kernel(const float* __restrict__ Wo, const float* __restrict__ bo,
             const float* __restrict__ ct,
             const float* __restrict__ gamma, const float* __restrict__ beta,
             float* __restrict__ ws, float* __restrict__ out) {
    __shared__ float r1[8], r2[8];
    __shared__ unsigned ticket;
    const int blk = blockIdx.x;
    const int b = blk >> 6, g = blk & 63;
    const int tid = threadIdx.x, wv = tid >> 6, lane = tid & 63;

    {
        int r = g * 8 + wv;
        const float4* ov = (const float4*)(ws + O0_OFF + (size_t)b * D_);
        float4 oa = ov[lane * 2], ob = ov[lane * 2 + 1];
        const float4* row = (const float4*)(Wo + (size_t)r * D_);
        float4 a = row[lane * 2], c = row[lane * 2 + 1];
        float acc = dot8(a, oa, c, ob);
        acc = wave_reduce_sum(acc);
        if (lane == 0) ws[Y_OFF + b * D_ + r] = acc + bo[r] + ct[r];
    }
    __syncthreads();                      // all 8 waves' y-stores issued
    if (tid == 0)
        ticket = __hip_atomic_fetch_add((unsigned*)ws + CNT_OFF + b, 1u,
                                        __ATOMIC_ACQ_REL, __HIP_MEMORY_SCOPE_AGENT);
    __syncthreads();
    if (ticket != 63) return;             // not the last block of batch b

    // LN for batch b (proven body); y-writes of all 64 blocks visible via the
    // acq_rel RMW chain on cnt[b] (release sequence).
    {
        float v = ws[Y_OFF + b * D_ + tid];
        float s1 = v, s2 = v * v;
        #pragma unroll
        for (int off = 32; off > 0; off >>= 1) {
            s1 += __shfl_down(s1, off, 64);
            s2 += __shfl_down(s2, off, 64);
        }
        if (lane == 0) { r1[wv] = s1; r2[wv] = s2; }
        __syncthreads();
        if (tid == 0) {
            float a = 0.f, c = 0.f;
            for (int i = 0; i < 8; ++i) { a += r1[i]; c += r2[i]; }
            r1[0] = a; r2[0] = c;
        }
        __syncthreads();
        float mean = r1[0] * (1.0f / D_);
        float var  = r2[0] * (1.0f / D_) - mean * mean;
        float rinv = rsqrtf(var + 1e-5f);
        out[b * D_ + tid] = (v - mean) * rinv * gamma[tid] + beta[tid];
    }
}

extern "C" void kernel_launch(void* const* d_in, const int* in_sizes, int n_in,
                              void* d_out, int out_size, void* d_ws, size_t ws_size,
                              hipStream_t stream) {
    const float* nf    = (const float*)d_in[0];   // node_feat [B,N,D]
    // d_in[1] edge_weights, d_in[2] adj_matrix: not needed for CLS-row output
    const float* masks = (const float*)d_in[3];   // [B,N]
    const float* ct    = (const float*)d_in[4];   // [D]
    const float* Wq    = (const float*)d_in[5];
    const float* bq    = (const float*)d_in[6];
    const float* Wk    = (const float*)d_in[7];
    // d_in[8] bk dropped (softmax shift-invariance)
    const float* Wv    = (const float*)d_in[9];
    const float* bv    = (const float*)d_in[10];
    const float* Wo    = (const float*)d_in[11];
    const float* bo    = (const float*)d_in[12];
    const float* gamma = (const float*)d_in[13];
    const float* beta  = (const float*)d_in[14];
    float* ws  = (float*)d_ws;
    float* out = (float*)d_out;

    // 4 dispatches, stream-ordered deps; only non-boundary sync is ONE ticket RMW
    // per K4 block (no polling — R1/R2/R4 lesson: polling costs 15-80us).
    hipLaunchKernelGGL(setup_kernel,       dim3(64),   dim3(512), 0, stream,
                       ct, Wq, bq, Wk, ws);
    hipLaunchKernelGGL(scores_wsum_kernel, dim3(NBLK), dim3(512), 0, stream,
                       nf, masks, ws);
    hipLaunchKernelGGL(wv_kernel,          dim3(256),  dim3(512), 0, stream,
                       Wv, bv, ct, ws);
    hipLaunchKernelGGL(wo_ln_kernel,       dim3(256),  dim3(512), 0, stream,
                       Wo, bo, ct, gamma, beta, ws, out);
}